// Round 14
// baseline (220.853 us; speedup 1.0000x reference)
//
#include <hip/hip_runtime.h>
#include <hip/hip_bf16.h>
#include <math.h>

// EpisodicMemory fused pipeline for MI355X (gfx950).
// B=16384, HID=1024, SLOTS=64, KD=32.
// Round 14: kill k_gemm's 38us fixed cost. Epilogue scatter (2B xv reads from
// A + 2B yb writes, 64 cache lines/instr) replaced by: xv extracted from sA
// during K-tiles 2*colblk/2*colblk+1 (LDS, numerics-identical), and y staged
// in smem (XOR-swizzled) then written with coalesced 16B stores.
// k_gemm core unchanged: algebraic form (K=1088 + retrieved tile), 256x256
// tile, 1024 threads, 64KB LDS, both-sides chunk swizzle, 2-barrier loop.

typedef float    f32x4 __attribute__((ext_vector_type(4)));
typedef short    s16x8 __attribute__((ext_vector_type(8)));
typedef unsigned short u16;
typedef unsigned short u16x8 __attribute__((ext_vector_type(8)));

#define MFMA_BF16(a,b,c) __builtin_amdgcn_mfma_f32_16x16x32_bf16((a),(b),(c),0,0,0)

__device__ __forceinline__ void async16(void* lds, const void* g) {
  __builtin_amdgcn_global_load_lds((const __attribute__((address_space(1))) void*)g,
                                   (__attribute__((address_space(3))) void*)lds, 16, 0, 0);
}

__device__ __forceinline__ u16 f2bf(float f) {
  unsigned u = __float_as_uint(f);
  u += 0x7fffu + ((u >> 16) & 1u);   // RNE
  return (u16)(u >> 16);
}
__device__ __forceinline__ float bf2f(u16 h) {
  return __uint_as_float(((unsigned)h) << 16);
}
__device__ __forceinline__ int ocol_of(int p) { return ((p >> 5) << 4) + (p & 15); }

// ---------------- K1: fused front ------------------------------------------
// blocks 0..255:   x->bf16 into A_ext + qk MFMA + softmax -> attn cols
// blocks 256..287: gate/out LEFT halves -> Wcat_ext[.][0..1023] (interleaved)
// blocks 288..319: Vcat transpose + PV mini-GEMM -> Wcat_ext[.][1024..1087]
__global__ __launch_bounds__(256) void k_front(
    const float* __restrict__ x, const float* __restrict__ gate_w,
    const float* __restrict__ out_w, const float* __restrict__ key_w,
    const float* __restrict__ mem_vals, const float* __restrict__ mem_keys,
    const float* __restrict__ pos_table, const int* __restrict__ slot_order,
    const float* __restrict__ mem_age, const float* __restrict__ mem_conf,
    u16* __restrict__ A, u16* __restrict__ Wcat, u16* __restrict__ Vcat) {
  const int b = blockIdx.x, tid = threadIdx.x;

  if (b >= 288) {            // ---- Vcat + PV mini-GEMM (64 p-rows each) ----
    const int pb = (b - 288) * 64;
    for (int e = tid; e < 64*64; e += 256) {
      int pl = e >> 6, s = e & 63;
      int p = pb + pl;
      Vcat[(size_t)p*64 + s] = f2bf(mem_vals[(size_t)s*1024 + ocol_of(p)]);
    }
    __shared__ __align__(16) u16 sW[64*80];
    __shared__ __align__(16) u16 sV[64*80];
    const int lane = tid & 63, w = tid >> 6;
    const int ln15 = lane & 15, hi = lane >> 4;
    f32x4 acc[4];
    #pragma unroll
    for (int n = 0; n < 4; n++) acc[n] = {0.f,0.f,0.f,0.f};
    for (int kt = 0; kt < 16; ++kt) {
      #pragma unroll
      for (int j = 0; j < 4; j++) {
        int idx = tid + j*256;
        int row = idx >> 4, g4 = idx & 15;
        int p = pb + row;
        const float* wsrc = ((p >> 4) & 1) ? out_w : gate_w;
        float4 v = *(const float4*)&wsrc[(size_t)ocol_of(p)*2048 + 1024 + kt*64 + g4*4];
        ushort4 o; o.x=f2bf(v.x); o.y=f2bf(v.y); o.z=f2bf(v.z); o.w=f2bf(v.w);
        *(ushort4*)&sW[row*80 + g4*4] = o;
        float4 u = *(const float4*)&mem_vals[(size_t)row*1024 + kt*64 + g4*4];
        ushort4 p2; p2.x=f2bf(u.x); p2.y=f2bf(u.y); p2.z=f2bf(u.z); p2.w=f2bf(u.w);
        *(ushort4*)&sV[row*80 + g4*4] = p2;
      }
      __syncthreads();
      #pragma unroll
      for (int kk = 0; kk < 2; kk++) {
        int kb = kk*32 + hi*8;
        s16x8 a = *(const s16x8*)&sW[(w*16 + ln15)*80 + kb];
        #pragma unroll
        for (int n = 0; n < 4; n++) {
          s16x8 bv = *(const s16x8*)&sV[(n*16 + ln15)*80 + kb];
          acc[n] = MFMA_BF16(a, bv, acc[n]);
        }
      }
      __syncthreads();
    }
    #pragma unroll
    for (int n = 0; n < 4; n++)
      #pragma unroll
      for (int i = 0; i < 4; i++) {
        int p = pb + w*16 + hi*4 + i;
        Wcat[(size_t)p*1088 + 1024 + n*16 + ln15] = f2bf(acc[n][i]);
      }
    return;
  }

  if (b >= 256) {            // ---- left halves -> Wcat_ext ----
    for (int g = (b-256)*256 + tid; g < 524288; g += 32*256) {
      float4 v; int t, pb2;
      if (g < 262144) { t = g;          v = *(const float4*)&gate_w[(size_t)(t>>8)*2048 + (t&255)*4]; pb2 = 0; }
      else            { t = g - 262144; v = *(const float4*)&out_w [(size_t)(t>>8)*2048 + (t&255)*4]; pb2 = 16; }
      int row = t >> 8, grp = t & 255;
      int p = ((row>>4)<<5) + pb2 + (row&15);
      ushort4 o; o.x=f2bf(v.x); o.y=f2bf(v.y); o.z=f2bf(v.z); o.w=f2bf(v.w);
      *(ushort4*)(Wcat + ((size_t)p*1088 + grp*4)) = o;
    }
    return;
  }

  // ---- main: x->bf16, qk, softmax, attn ----
  __shared__ __align__(16) u16 sX[64*72];    // x tile bf16, padded stride 72
  __shared__ __align__(16) u16 sWk[32*72];   // key_w slice bf16
  __shared__ float sQK[64*33];
  __shared__ float sK[64*33];
  __shared__ float sBias[64];
  __shared__ float sQn[64*32];

  const int lane = tid & 63, w = tid >> 6;
  const int ln15 = lane & 15, hi = lane >> 4;
  const size_t r0 = (size_t)b * 64;

  if (tid < 64) {            // in-block slot prep (inputs tiny, L3-resident)
    int s = tid;
    float age  = mem_age[s];
    float freq = fmaxf(age, 1.0f);
    float fm = freq;
    #pragma unroll
    for (int o = 32; o; o >>= 1) fm = fmaxf(fm, __shfl_xor(fm, o));
    float freq_norm = logf(freq + 1.0f) / (logf(fm + 2.0f) + 1e-8f);
    float recency = expf(-age * (1.0f/200.0f));
    sBias[s] = 0.2f*recency + 0.15f*freq_norm + 0.1f*mem_conf[s] + 0.08f;

    int idx = slot_order[s] & 63;
    float k[32]; float ss = 0.f;
    #pragma unroll
    for (int d = 0; d < 32; d++) {
      float v = mem_keys[s*32+d] + 0.1f*pos_table[idx*32+d];
      k[d] = v; ss += v*v;
    }
    float inv = 1.0f / fmaxf(sqrtf(ss), 1e-12f);
    #pragma unroll
    for (int d = 0; d < 32; d++) sK[s*33+d] = k[d]*inv;
  }

  // ---- qk = x @ key_w^T via MFMA, fused with x->bf16 conversion ----
  f32x4 acc0 = {0.f,0.f,0.f,0.f}, acc1 = {0.f,0.f,0.f,0.f};
  const int xrow = tid >> 4, xc4 = tid & 15;
  for (int k0 = 0; k0 < 1024; k0 += 64) {
    #pragma unroll
    for (int j = 0; j < 4; j++) {
      int row = xrow + j*16;
      float4 v = *(const float4*)&x[(r0+row)*1024 + k0 + xc4*4];
      ushort4 o; o.x=f2bf(v.x); o.y=f2bf(v.y); o.z=f2bf(v.z); o.w=f2bf(v.w);
      *(ushort4*)&sX[row*72 + xc4*4] = o;
      *(ushort4*)&A[(r0+row)*1088 + k0 + xc4*4] = o;    // A_ext left (x bf16)
    }
    #pragma unroll
    for (int j = 0; j < 2; j++) {                        // key_w slice -> bf16
      int idx = tid + j*256;
      int row = idx >> 4, c4 = idx & 15;
      float4 v = *(const float4*)&key_w[(size_t)row*1024 + k0 + c4*4];
      ushort4 o; o.x=f2bf(v.x); o.y=f2bf(v.y); o.z=f2bf(v.z); o.w=f2bf(v.w);
      *(ushort4*)&sWk[row*72 + c4*4] = o;
    }
    __syncthreads();
    #pragma unroll
    for (int kk = 0; kk < 2; kk++) {
      int kb = kk*32 + hi*8;
      s16x8 a  = *(const s16x8*)&sX[(w*16 + ln15)*72 + kb];
      s16x8 b0 = *(const s16x8*)&sWk[ln15*72 + kb];
      s16x8 b1 = *(const s16x8*)&sWk[(16+ln15)*72 + kb];
      acc0 = MFMA_BF16(a, b0, acc0);
      acc1 = MFMA_BF16(a, b1, acc1);
    }
    __syncthreads();
  }
  #pragma unroll
  for (int i = 0; i < 4; i++) {
    sQK[(w*16 + hi*4 + i)*33 + ln15]      = acc0[i];
    sQK[(w*16 + hi*4 + i)*33 + 16 + ln15] = acc1[i];
  }
  __syncthreads();

  // ---- softmax over 64 slots; write attn bf16 to A_ext[1024..1087] ----
  int d = lane & 31;
  for (int j = 0; j < 16; j++) {
    int rl = w*16 + j;
    float v = sQK[rl*33 + d];
    float sq = v*v;
    #pragma unroll
    for (int o = 16; o; o >>= 1) sq += __shfl_xor(sq, o);   // 32-group sum
    float qn = v / fmaxf(sqrtf(sq), 1e-12f);
    if (lane < 32) sQn[rl*32 + d] = qn;
    float accs = 0.f;
    #pragma unroll
    for (int dd = 0; dd < 32; dd++) accs += sK[lane*33+dd] * sQn[rl*32+dd];
    float sim = accs * 0.17677669529663687f;   // 1/sqrt(32)
    float sal = fminf(fmaxf(0.45f*sim + sBias[lane], 0.0f), 1.0f);
    float mx = sal;
    #pragma unroll
    for (int o = 32; o; o >>= 1) mx = fmaxf(mx, __shfl_xor(mx, o));
    float e = expf(sal - mx);
    float sm = e;
    #pragma unroll
    for (int o = 32; o; o >>= 1) sm += __shfl_xor(sm, o);
    A[(r0 + rl)*1088 + 1024 + lane] = f2bf(e / sm);
  }
}

// ---------------- K2: GEMM (K=1088 + retrieved tile) + fused epilogue -------
// C = A_ext[16384,1088] @ Wcat_ext[2048,1088]^T  (gate/out interleaved),
// then one extra K-tile: acc_r = attn-tile @ Vcat-slice = retrieved values.
// 256x256 tile, 16 waves (4x4, wave 64x64), BK=64, single 64KB LDS buffer.
// xv captured from sA at kt=2*colblk(+1); y staged in smem, coalesced out.
__global__ __launch_bounds__(1024, 2) void k_gemm(
    const u16* __restrict__ A, const u16* __restrict__ Wcat,
    const u16* __restrict__ Vcat, const float* __restrict__ out_b,
    const float* __restrict__ gate_b, u16* __restrict__ yb) {
  __shared__ __align__(16) u16 smem[32768];   // 64KB: sA|sB, later y staging
  u16* sA = smem;
  u16* sB = smem + 16384;

  const int tid = threadIdx.x, lane = tid & 63, w = tid >> 6;
  const int ln15 = lane & 15, hi = lane >> 4, p7 = ln15 & 7;
  const int wm = w >> 2, wn = w & 3;        // 4x4 waves, wave = 64x64

  const int colblk = blockIdx.x & 7;        // XCD-resident weight panel
  const int rowblk = blockIdx.x >> 3;       // 0..63
  const size_t r0 = (size_t)rowblk * 256;
  const size_t c0 = (size_t)colblk * 256;

  const u16* gA = A    + r0 * 1088;
  const u16* gB = Wcat + c0 * 1088;
  const u16* gV = Vcat + c0 * 64;

  // staging: 2048 chunks of 16B per side, 2/thread each; physical chunk pc
  // of row r holds logical chunk pc ^ (r&7) (inverse swizzle on global src).
  int offA[2], offB[2], offV[2];
  #pragma unroll
  for (int j = 0; j < 2; j++) {
    int c = tid + j*1024, row = c >> 3, pc = c & 7;
    int sw = ((pc ^ (row & 7)) << 3);
    offA[j] = row*1088 + sw;
    offB[j] = row*1088 + sw;
    offV[j] = row*64   + sw;
  }

  const int ck0 = (hi ^ p7) * 8;            // kk=0: logical chunk hi
  const int ck1 = ((4 | hi) ^ p7) * 8;      // kk=1: logical chunk 4|hi
  const int arow = (wm*64 + ln15) * 64;     // + m*1024
  const int brow = (wn*64 + ln15) * 64;     // + n*1024

  f32x4 acc[4][4], accr[4][2];
  #pragma unroll
  for (int m = 0; m < 4; m++) {
    #pragma unroll
    for (int n = 0; n < 4; n++) acc[m][n] = {0.f, 0.f, 0.f, 0.f};
    accr[m][0] = {0.f,0.f,0.f,0.f}; accr[m][1] = {0.f,0.f,0.f,0.f};
  }
  float xv[2][4][4];   // x values for the blend, captured from sA in-loop

  #pragma unroll 1
  for (int kt = 0; kt < 17; ++kt) {
    const int ko = kt * 64;
    #pragma unroll
    for (int j = 0; j < 2; j++) {
      async16(&sA[(tid + j*1024)*8], gA + offA[j] + ko);
      async16(&sB[(tid + j*1024)*8], gB + offB[j] + ko);
    }
    __syncthreads();   // drains vmcnt(0): staged tile visible to all waves
    #pragma unroll
    for (int kk = 0; kk < 2; kk++) {
      const int ck = kk ? ck1 : ck0;
      s16x8 af[4], bfr[4];
      #pragma unroll
      for (int m = 0; m < 4; m++) af[m]  = *(const s16x8*)&sA[arow + m*1024 + ck];
      #pragma unroll
      for (int n = 0; n < 4; n++) bfr[n] = *(const s16x8*)&sB[brow + n*1024 + ck];
      #pragma unroll
      for (int m = 0; m < 4; m++)
        #pragma unroll
        for (int n = 0; n < 4; n++)
          acc[m][n] = MFMA_BF16(af[m], bfr[n], acc[m][n]);
    }
    // capture xv while this block's ocol columns are resident in sA
    if ((kt >> 1) == colblk && (wn >> 1) == (kt & 1)) {
      #pragma unroll
      for (int s = 0; s < 2; s++) {
        int c = (wn & 1)*32 + s*16 + ln15;          // col within this K-tile
        #pragma unroll
        for (int m = 0; m < 4; m++)
          #pragma unroll
          for (int i = 0; i < 4; i++) {
            int r = wm*64 + m*16 + hi*4 + i;
            xv[s][m][i] = bf2f(sA[r*64 + (((c >> 3) ^ (r & 7)) << 3) + (c & 7)]);
          }
      }
    }
    __syncthreads();   // tile fully consumed before next stage overwrites
  }

  // retrieved pass: sA still holds kt=16 (attn tile); stage Vcat slice -> sB
  #pragma unroll
  for (int j = 0; j < 2; j++) async16(&sB[(tid + j*1024)*8], gV + offV[j]);
  __syncthreads();
  #pragma unroll
  for (int kk = 0; kk < 2; kk++) {
    const int ck = kk ? ck1 : ck0;
    s16x8 af[4], bf0, bf1;
    #pragma unroll
    for (int m = 0; m < 4; m++) af[m] = *(const s16x8*)&sA[arow + m*1024 + ck];
    bf0 = *(const s16x8*)&sB[brow + ck];            // n-tile 0 (gate cols s=0)
    bf1 = *(const s16x8*)&sB[brow + 2*1024 + ck];   // n-tile 2 (gate cols s=1)
    #pragma unroll
    for (int m = 0; m < 4; m++) {
      accr[m][0] = MFMA_BF16(af[m], bf0, accr[m][0]);
      accr[m][1] = MFMA_BF16(af[m], bf1, accr[m][1]);
    }
  }
  __syncthreads();   // all smem reads done; smem becomes y staging buffer

  // epilogue: compute y, stage bf16 into smem [256][128] (XOR-swizzled cols)
  #pragma unroll
  for (int s = 0; s < 2; s++) {
    int c = wn*32 + s*16 + ln15;                    // local out col 0..127
    int ocol = colblk*128 + c;
    float gbv = gate_b[ocol], obv = out_b[ocol];
    #pragma unroll
    for (int m = 0; m < 4; m++) {
      #pragma unroll
      for (int i = 0; i < 4; i++) {
        int r = wm*64 + m*16 + hi*4 + i;            // local row 0..255
        float gg = acc[m][s*2+0][i] + gbv;
        float go = acc[m][s*2+1][i] + obv;
        float h  = 0.5f*go*(1.0f + erff(go*0.70710678118654752f));  // exact gelu
        float sg = 1.0f/(1.0f + __expf(-gg));
        float yv = h + sg*accr[m][s][i] + (1.0f - sg)*xv[s][m][i];
        smem[r*128 + (c ^ ((r & 15) << 3))] = f2bf(yv);
      }
    }
  }
  __syncthreads();

  // coalesced copy-out: 4096 chunks of 16B; thread handles tid + j*1024
  #pragma unroll
  for (int j = 0; j < 4; j++) {
    int chunk = tid + j*1024;
    int row = chunk >> 4;                           // 16 chunks per row
    int cc = (chunk & 15) << 3;                     // col start, 8-aligned
    u16x8 v = *(const u16x8*)&smem[row*128 + (cc ^ ((row & 15) << 3))];
    *(u16x8*)&yb[(r0 + row)*1024 + colblk*128 + cc] = v;
  }
}

// ---------------- K3: LayerNorm (bf16 in -> f32 out, wave per row) ----------
__global__ __launch_bounds__(256) void k_ln(const u16* __restrict__ yb,
                                            const float* __restrict__ g,
                                            const float* __restrict__ b,
                                            float* __restrict__ out) {
  int row  = blockIdx.x*4 + (threadIdx.x >> 6);
  int lane = threadIdx.x & 63;
  const u16* p = yb + (size_t)row*1024 + lane*16;
  u16x8 h0 = *(const u16x8*)p;
  u16x8 h1 = *(const u16x8*)(p + 8);
  float v[16];
  #pragma unroll
  for (int i = 0; i < 8; i++) { v[i] = bf2f((u16)h0[i]); v[8+i] = bf2f((u16)h1[i]); }
  float s = 0.f;
  #pragma unroll
  for (int i = 0; i < 16; i++) s += v[i];
  #pragma unroll
  for (int o = 32; o; o >>= 1) s += __shfl_xor(s, o);
  float mu = s * (1.0f/1024.0f);
  float vs = 0.f;
  #pragma unroll
  for (int i = 0; i < 16; i++) { float d0 = v[i]-mu; vs += d0*d0; }
  #pragma unroll
  for (int o = 32; o; o >>= 1) vs += __shfl_xor(vs, o);
  float inv = 1.0f / sqrtf(vs*(1.0f/1024.0f) + 1e-5f);
  const float4* gp = (const float4*)(g + lane*16);
  const float4* bp = (const float4*)(b + lane*16);
  float4* op = (float4*)(out + (size_t)row*1024 + lane*16);
  #pragma unroll
  for (int i = 0; i < 4; i++) {
    float4 gv = gp[i], bv = bp[i], o4;
    o4.x = (v[i*4+0]-mu)*inv*gv.x + bv.x;
    o4.y = (v[i*4+1]-mu)*inv*gv.y + bv.y;
    o4.z = (v[i*4+2]-mu)*inv*gv.z + bv.z;
    o4.w = (v[i*4+3]-mu)*inv*gv.w + bv.w;
    op[i] = o4;
  }
}

// ---------------- launch ----------------------------------------------------
extern "C" void kernel_launch(void* const* d_in, const int* in_sizes, int n_in,
                              void* d_out, int out_size, void* d_ws, size_t ws_size,
                              hipStream_t stream) {
  const float* x         = (const float*)d_in[0];
  const float* key_w     = (const float*)d_in[1];
  const float* out_w     = (const float*)d_in[2];
  const float* out_b     = (const float*)d_in[3];
  const float* gate_w    = (const float*)d_in[4];
  const float* gate_b    = (const float*)d_in[5];
  const float* ln_g      = (const float*)d_in[6];
  const float* ln_b      = (const float*)d_in[7];
  const float* pos_table = (const float*)d_in[8];
  const float* mem_keys  = (const float*)d_in[9];
  const float* mem_vals  = (const float*)d_in[10];
  const float* mem_age   = (const float*)d_in[11];
  const float* mem_conf  = (const float*)d_in[12];
  const int*   slot_order= (const int*)d_in[13];

  char* ws = (char*)d_ws;
  u16*   A    = (u16*)(ws + 0);            // A_ext bf16 [16384][1088]  35.7 MB
  u16*   Wcat = (u16*)(ws + 36700160);     // Wcat_ext bf16 [2048][1088] 4.5 MB
  u16*   Vcat = (u16*)(ws + 41943040);     // Vcat bf16 [2048][64]     256 KB
  u16*   yb   = (u16*)(ws + 42205184);     // y bf16 [16384][1024]      32 MB
  float* y    = (float*)d_out;

  hipLaunchKernelGGL(k_front, dim3(320),  dim3(256),  0, stream,
                     x, gate_w, out_w, key_w, mem_vals, mem_keys, pos_table,
                     slot_order, mem_age, mem_conf, A, Wcat, Vcat);
  hipLaunchKernelGGL(k_gemm,  dim3(512),  dim3(1024), 0, stream,
                     A, Wcat, Vcat, out_b, gate_b, yb);
  hipLaunchKernelGGL(k_ln,    dim3(4096), dim3(256),  0, stream,
                     yb, ln_g, ln_b, y);
}

// Round 15
// 170.822 us; speedup vs baseline: 1.2929x; 1.2929x over previous
//
#include <hip/hip_runtime.h>
#include <hip/hip_bf16.h>
#include <math.h>

// EpisodicMemory fused pipeline for MI355X (gfx950).
// B=16384, HID=1024, SLOTS=64, KD=32.
// Round 15: k_gemm/k_ln reverted to round-13 (known-good 174.7us total).
// Single change: k_front main path register-prefetches next iteration's
// x/key_w float4 loads (T14 async-split) — only ~5 waves/CU there, so TLP
// can't hide HBM latency; ILP must.

typedef float    f32x4 __attribute__((ext_vector_type(4)));
typedef short    s16x8 __attribute__((ext_vector_type(8)));
typedef unsigned short u16;
typedef unsigned short u16x8 __attribute__((ext_vector_type(8)));

#define MFMA_BF16(a,b,c) __builtin_amdgcn_mfma_f32_16x16x32_bf16((a),(b),(c),0,0,0)

__device__ __forceinline__ void async16(void* lds, const void* g) {
  __builtin_amdgcn_global_load_lds((const __attribute__((address_space(1))) void*)g,
                                   (__attribute__((address_space(3))) void*)lds, 16, 0, 0);
}

__device__ __forceinline__ u16 f2bf(float f) {
  unsigned u = __float_as_uint(f);
  u += 0x7fffu + ((u >> 16) & 1u);   // RNE
  return (u16)(u >> 16);
}
__device__ __forceinline__ float bf2f(u16 h) {
  return __uint_as_float(((unsigned)h) << 16);
}
__device__ __forceinline__ int ocol_of(int p) { return ((p >> 5) << 4) + (p & 15); }

// ---------------- K1: fused front ------------------------------------------
// blocks 0..255:   x->bf16 into A_ext + qk MFMA + softmax -> attn cols
// blocks 256..287: gate/out LEFT halves -> Wcat_ext[.][0..1023] (interleaved)
// blocks 288..319: Vcat transpose + PV mini-GEMM -> Wcat_ext[.][1024..1087]
__global__ __launch_bounds__(256) void k_front(
    const float* __restrict__ x, const float* __restrict__ gate_w,
    const float* __restrict__ out_w, const float* __restrict__ key_w,
    const float* __restrict__ mem_vals, const float* __restrict__ mem_keys,
    const float* __restrict__ pos_table, const int* __restrict__ slot_order,
    const float* __restrict__ mem_age, const float* __restrict__ mem_conf,
    u16* __restrict__ A, u16* __restrict__ Wcat, u16* __restrict__ Vcat) {
  const int b = blockIdx.x, tid = threadIdx.x;

  if (b >= 288) {            // ---- Vcat + PV mini-GEMM (64 p-rows each) ----
    const int pb = (b - 288) * 64;
    for (int e = tid; e < 64*64; e += 256) {
      int pl = e >> 6, s = e & 63;
      int p = pb + pl;
      Vcat[(size_t)p*64 + s] = f2bf(mem_vals[(size_t)s*1024 + ocol_of(p)]);
    }
    __shared__ __align__(16) u16 sW[64*80];
    __shared__ __align__(16) u16 sV[64*80];
    const int lane = tid & 63, w = tid >> 6;
    const int ln15 = lane & 15, hi = lane >> 4;
    f32x4 acc[4];
    #pragma unroll
    for (int n = 0; n < 4; n++) acc[n] = {0.f,0.f,0.f,0.f};
    for (int kt = 0; kt < 16; ++kt) {
      #pragma unroll
      for (int j = 0; j < 4; j++) {
        int idx = tid + j*256;
        int row = idx >> 4, g4 = idx & 15;
        int p = pb + row;
        const float* wsrc = ((p >> 4) & 1) ? out_w : gate_w;
        float4 v = *(const float4*)&wsrc[(size_t)ocol_of(p)*2048 + 1024 + kt*64 + g4*4];
        ushort4 o; o.x=f2bf(v.x); o.y=f2bf(v.y); o.z=f2bf(v.z); o.w=f2bf(v.w);
        *(ushort4*)&sW[row*80 + g4*4] = o;
        float4 u = *(const float4*)&mem_vals[(size_t)row*1024 + kt*64 + g4*4];
        ushort4 p2; p2.x=f2bf(u.x); p2.y=f2bf(u.y); p2.z=f2bf(u.z); p2.w=f2bf(u.w);
        *(ushort4*)&sV[row*80 + g4*4] = p2;
      }
      __syncthreads();
      #pragma unroll
      for (int kk = 0; kk < 2; kk++) {
        int kb = kk*32 + hi*8;
        s16x8 a = *(const s16x8*)&sW[(w*16 + ln15)*80 + kb];
        #pragma unroll
        for (int n = 0; n < 4; n++) {
          s16x8 bv = *(const s16x8*)&sV[(n*16 + ln15)*80 + kb];
          acc[n] = MFMA_BF16(a, bv, acc[n]);
        }
      }
      __syncthreads();
    }
    #pragma unroll
    for (int n = 0; n < 4; n++)
      #pragma unroll
      for (int i = 0; i < 4; i++) {
        int p = pb + w*16 + hi*4 + i;
        Wcat[(size_t)p*1088 + 1024 + n*16 + ln15] = f2bf(acc[n][i]);
      }
    return;
  }

  if (b >= 256) {            // ---- left halves -> Wcat_ext ----
    for (int g = (b-256)*256 + tid; g < 524288; g += 32*256) {
      float4 v; int t, pb2;
      if (g < 262144) { t = g;          v = *(const float4*)&gate_w[(size_t)(t>>8)*2048 + (t&255)*4]; pb2 = 0; }
      else            { t = g - 262144; v = *(const float4*)&out_w [(size_t)(t>>8)*2048 + (t&255)*4]; pb2 = 16; }
      int row = t >> 8, grp = t & 255;
      int p = ((row>>4)<<5) + pb2 + (row&15);
      ushort4 o; o.x=f2bf(v.x); o.y=f2bf(v.y); o.z=f2bf(v.z); o.w=f2bf(v.w);
      *(ushort4*)(Wcat + ((size_t)p*1088 + grp*4)) = o;
    }
    return;
  }

  // ---- main: x->bf16, qk, softmax, attn ----
  __shared__ __align__(16) u16 sX[64*72];    // x tile bf16, padded stride 72
  __shared__ __align__(16) u16 sWk[32*72];   // key_w slice bf16
  __shared__ float sQK[64*33];
  __shared__ float sK[64*33];
  __shared__ float sBias[64];
  __shared__ float sQn[64*32];

  const int lane = tid & 63, w = tid >> 6;
  const int ln15 = lane & 15, hi = lane >> 4;
  const size_t r0 = (size_t)b * 64;

  if (tid < 64) {            // in-block slot prep (inputs tiny, L3-resident)
    int s = tid;
    float age  = mem_age[s];
    float freq = fmaxf(age, 1.0f);
    float fm = freq;
    #pragma unroll
    for (int o = 32; o; o >>= 1) fm = fmaxf(fm, __shfl_xor(fm, o));
    float freq_norm = logf(freq + 1.0f) / (logf(fm + 2.0f) + 1e-8f);
    float recency = expf(-age * (1.0f/200.0f));
    sBias[s] = 0.2f*recency + 0.15f*freq_norm + 0.1f*mem_conf[s] + 0.08f;

    int idx = slot_order[s] & 63;
    float k[32]; float ss = 0.f;
    #pragma unroll
    for (int d = 0; d < 32; d++) {
      float v = mem_keys[s*32+d] + 0.1f*pos_table[idx*32+d];
      k[d] = v; ss += v*v;
    }
    float inv = 1.0f / fmaxf(sqrtf(ss), 1e-12f);
    #pragma unroll
    for (int d = 0; d < 32; d++) sK[s*33+d] = k[d]*inv;
  }

  // ---- qk = x @ key_w^T via MFMA, fused with x->bf16 conversion.
  // Register prefetch (T14): issue it+1's loads before converting it.
  f32x4 acc0 = {0.f,0.f,0.f,0.f}, acc1 = {0.f,0.f,0.f,0.f};
  const int xrow = tid >> 4, xc4 = tid & 15;
  const int krow = tid >> 4, kc4 = tid & 15;          // for key_w (rows 0..31)
  float4 cx[4], ck[2];
  #pragma unroll
  for (int j = 0; j < 4; j++)
    cx[j] = *(const float4*)&x[(r0 + xrow + j*16)*1024 + xc4*4];
  #pragma unroll
  for (int j = 0; j < 2; j++)
    ck[j] = *(const float4*)&key_w[(size_t)(krow + j*16)*1024 + kc4*4];

  #pragma unroll 1
  for (int it = 0; it < 16; ++it) {
    const int k0 = it*64;
    const int k0n = (it < 15) ? k0 + 64 : k0;        // last iter: harmless re-read
    float4 nx[4], nk[2];
    #pragma unroll
    for (int j = 0; j < 4; j++)
      nx[j] = *(const float4*)&x[(r0 + xrow + j*16)*1024 + k0n + xc4*4];
    #pragma unroll
    for (int j = 0; j < 2; j++)
      nk[j] = *(const float4*)&key_w[(size_t)(krow + j*16)*1024 + k0n + kc4*4];

    #pragma unroll
    for (int j = 0; j < 4; j++) {
      int row = xrow + j*16;
      ushort4 o; o.x=f2bf(cx[j].x); o.y=f2bf(cx[j].y); o.z=f2bf(cx[j].z); o.w=f2bf(cx[j].w);
      *(ushort4*)&sX[row*72 + xc4*4] = o;
      *(ushort4*)&A[(r0+row)*1088 + k0 + xc4*4] = o;  // A_ext left (x bf16)
    }
    #pragma unroll
    for (int j = 0; j < 2; j++) {
      int row = krow + j*16;
      ushort4 o; o.x=f2bf(ck[j].x); o.y=f2bf(ck[j].y); o.z=f2bf(ck[j].z); o.w=f2bf(ck[j].w);
      *(ushort4*)&sWk[row*72 + kc4*4] = o;
    }
    __syncthreads();
    #pragma unroll
    for (int kk = 0; kk < 2; kk++) {
      int kb = kk*32 + hi*8;
      s16x8 a  = *(const s16x8*)&sX[(w*16 + ln15)*72 + kb];
      s16x8 b0 = *(const s16x8*)&sWk[ln15*72 + kb];
      s16x8 b1 = *(const s16x8*)&sWk[(16+ln15)*72 + kb];
      acc0 = MFMA_BF16(a, b0, acc0);
      acc1 = MFMA_BF16(a, b1, acc1);
    }
    __syncthreads();
    #pragma unroll
    for (int j = 0; j < 4; j++) cx[j] = nx[j];
    ck[0] = nk[0]; ck[1] = nk[1];
  }
  #pragma unroll
  for (int i = 0; i < 4; i++) {
    sQK[(w*16 + hi*4 + i)*33 + ln15]      = acc0[i];
    sQK[(w*16 + hi*4 + i)*33 + 16 + ln15] = acc1[i];
  }
  __syncthreads();

  // ---- softmax over 64 slots; write attn bf16 to A_ext[1024..1087] ----
  int d = lane & 31;
  for (int j = 0; j < 16; j++) {
    int rl = w*16 + j;
    float v = sQK[rl*33 + d];
    float sq = v*v;
    #pragma unroll
    for (int o = 16; o; o >>= 1) sq += __shfl_xor(sq, o);   // 32-group sum
    float qn = v / fmaxf(sqrtf(sq), 1e-12f);
    if (lane < 32) sQn[rl*32 + d] = qn;
    float accs = 0.f;
    #pragma unroll
    for (int dd = 0; dd < 32; dd++) accs += sK[lane*33+dd] * sQn[rl*32+dd];
    float sim = accs * 0.17677669529663687f;   // 1/sqrt(32)
    float sal = fminf(fmaxf(0.45f*sim + sBias[lane], 0.0f), 1.0f);
    float mx = sal;
    #pragma unroll
    for (int o = 32; o; o >>= 1) mx = fmaxf(mx, __shfl_xor(mx, o));
    float e = expf(sal - mx);
    float sm = e;
    #pragma unroll
    for (int o = 32; o; o >>= 1) sm += __shfl_xor(sm, o);
    A[(r0 + rl)*1088 + 1024 + lane] = f2bf(e / sm);
  }
}

// ---------------- K2: GEMM (K=1088 + retrieved tile) + fused epilogue -------
// (round-13 version, verbatim)
__global__ __launch_bounds__(1024, 2) void k_gemm(
    const u16* __restrict__ A, const u16* __restrict__ Wcat,
    const u16* __restrict__ Vcat, const float* __restrict__ out_b,
    const float* __restrict__ gate_b, u16* __restrict__ yb) {
  __shared__ __align__(16) u16 sA[16384];   // 256 rows x 64 (swizzled)
  __shared__ __align__(16) u16 sB[16384];   // 256 rows x 64 (swizzled)

  const int tid = threadIdx.x, lane = tid & 63, w = tid >> 6;
  const int ln15 = lane & 15, hi = lane >> 4, p7 = ln15 & 7;
  const int wm = w >> 2, wn = w & 3;        // 4x4 waves, wave = 64x64

  const int colblk = blockIdx.x & 7;        // XCD-resident weight panel
  const int rowblk = blockIdx.x >> 3;       // 0..63
  const size_t r0 = (size_t)rowblk * 256;
  const size_t c0 = (size_t)colblk * 256;

  const u16* gA = A    + r0 * 1088;
  const u16* gB = Wcat + c0 * 1088;
  const u16* gV = Vcat + c0 * 64;

  int offA[2], offB[2], offV[2];
  #pragma unroll
  for (int j = 0; j < 2; j++) {
    int c = tid + j*1024, row = c >> 3, pc = c & 7;
    int sw = ((pc ^ (row & 7)) << 3);
    offA[j] = row*1088 + sw;
    offB[j] = row*1088 + sw;
    offV[j] = row*64   + sw;
  }

  const int ck0 = (hi ^ p7) * 8;            // kk=0: logical chunk hi
  const int ck1 = ((4 | hi) ^ p7) * 8;      // kk=1: logical chunk 4|hi
  const int arow = (wm*64 + ln15) * 64;     // + m*1024
  const int brow = (wn*64 + ln15) * 64;     // + n*1024

  f32x4 acc[4][4], accr[4][2];
  #pragma unroll
  for (int m = 0; m < 4; m++) {
    #pragma unroll
    for (int n = 0; n < 4; n++) acc[m][n] = {0.f, 0.f, 0.f, 0.f};
    accr[m][0] = {0.f,0.f,0.f,0.f}; accr[m][1] = {0.f,0.f,0.f,0.f};
  }

  #pragma unroll 1
  for (int kt = 0; kt < 17; ++kt) {
    const int ko = kt * 64;
    #pragma unroll
    for (int j = 0; j < 2; j++) {
      async16(&sA[(tid + j*1024)*8], gA + offA[j] + ko);
      async16(&sB[(tid + j*1024)*8], gB + offB[j] + ko);
    }
    __syncthreads();   // drains vmcnt(0): staged tile visible to all waves
    #pragma unroll
    for (int kk = 0; kk < 2; kk++) {
      const int ck = kk ? ck1 : ck0;
      s16x8 af[4], bfr[4];
      #pragma unroll
      for (int m = 0; m < 4; m++) af[m]  = *(const s16x8*)&sA[arow + m*1024 + ck];
      #pragma unroll
      for (int n = 0; n < 4; n++) bfr[n] = *(const s16x8*)&sB[brow + n*1024 + ck];
      #pragma unroll
      for (int m = 0; m < 4; m++)
        #pragma unroll
        for (int n = 0; n < 4; n++)
          acc[m][n] = MFMA_BF16(af[m], bfr[n], acc[m][n]);
    }
    __syncthreads();   // tile fully consumed before next stage overwrites
  }

  // retrieved pass: sA still holds kt=16 (attn tile); stage Vcat slice -> sB
  #pragma unroll
  for (int j = 0; j < 2; j++) async16(&sB[(tid + j*1024)*8], gV + offV[j]);
  __syncthreads();
  #pragma unroll
  for (int kk = 0; kk < 2; kk++) {
    const int ck = kk ? ck1 : ck0;
    s16x8 af[4], bf0, bf1;
    #pragma unroll
    for (int m = 0; m < 4; m++) af[m] = *(const s16x8*)&sA[arow + m*1024 + ck];
    bf0 = *(const s16x8*)&sB[brow + ck];            // n-tile 0 (gate cols s=0)
    bf1 = *(const s16x8*)&sB[brow + 2*1024 + ck];   // n-tile 2 (gate cols s=1)
    #pragma unroll
    for (int m = 0; m < 4; m++) {
      accr[m][0] = MFMA_BF16(af[m], bf0, accr[m][0]);
      accr[m][1] = MFMA_BF16(af[m], bf1, accr[m][1]);
    }
  }

  // epilogue: acc[m][2s]=gate_pre, acc[m][2s+1]=out_pre, accr[m][s]=retrieved
  #pragma unroll
  for (int s = 0; s < 2; s++) {
    int ocol = colblk*128 + wn*32 + s*16 + ln15;
    float gbv = gate_b[ocol], obv = out_b[ocol];
    #pragma unroll
    for (int m = 0; m < 4; m++) {
      #pragma unroll
      for (int i = 0; i < 4; i++) {
        size_t r = r0 + wm*64 + m*16 + hi*4 + i;
        float gg = acc[m][s*2+0][i] + gbv;
        float go = acc[m][s*2+1][i] + obv;
        float h  = 0.5f*go*(1.0f + erff(go*0.70710678118654752f));  // exact gelu
        float sg = 1.0f/(1.0f + __expf(-gg));
        float rv = accr[m][s][i];
        float xv = bf2f(A[r*1088 + ocol]);
        yb[r*1024 + ocol] = f2bf(h + sg*rv + (1.0f - sg)*xv);
      }
    }
  }
}

// ---------------- K3: LayerNorm (bf16 in -> f32 out, wave per row) ----------
__global__ __launch_bounds__(256) void k_ln(const u16* __restrict__ yb,
                                            const float* __restrict__ g,
                                            const float* __restrict__ b,
                                            float* __restrict__ out) {
  int row  = blockIdx.x*4 + (threadIdx.x >> 6);
  int lane = threadIdx.x & 63;
  const u16* p = yb + (size_t)row*1024 + lane*16;
  u16x8 h0 = *(const u16x8*)p;
  u16x8 h1 = *(const u16x8*)(p + 8);
  float v[16];
  #pragma unroll
  for (int i = 0; i < 8; i++) { v[i] = bf2f((u16)h0[i]); v[8+i] = bf2f((u16)h1[i]); }
  float s = 0.f;
  #pragma unroll
  for (int i = 0; i < 16; i++) s += v[i];
  #pragma unroll
  for (int o = 32; o; o >>= 1) s += __shfl_xor(s, o);
  float mu = s * (1.0f/1024.0f);
  float vs = 0.f;
  #pragma unroll
  for (int i = 0; i < 16; i++) { float d0 = v[i]-mu; vs += d0*d0; }
  #pragma unroll
  for (int o = 32; o; o >>= 1) vs += __shfl_xor(vs, o);
  float inv = 1.0f / sqrtf(vs*(1.0f/1024.0f) + 1e-5f);
  const float4* gp = (const float4*)(g + lane*16);
  const float4* bp = (const float4*)(b + lane*16);
  float4* op = (float4*)(out + (size_t)row*1024 + lane*16);
  #pragma unroll
  for (int i = 0; i < 4; i++) {
    float4 gv = gp[i], bv = bp[i], o4;
    o4.x = (v[i*4+0]-mu)*inv*gv.x + bv.x;
    o4.y = (v[i*4+1]-mu)*inv*gv.y + bv.y;
    o4.z = (v[i*4+2]-mu)*inv*gv.z + bv.z;
    o4.w = (v[i*4+3]-mu)*inv*gv.w + bv.w;
    op[i] = o4;
  }
}

// ---------------- launch ----------------------------------------------------
extern "C" void kernel_launch(void* const* d_in, const int* in_sizes, int n_in,
                              void* d_out, int out_size, void* d_ws, size_t ws_size,
                              hipStream_t stream) {
  const float* x         = (const float*)d_in[0];
  const float* key_w     = (const float*)d_in[1];
  const float* out_w     = (const float*)d_in[2];
  const float* out_b     = (const float*)d_in[3];
  const float* gate_w    = (const float*)d_in[4];
  const float* gate_b    = (const float*)d_in[5];
  const float* ln_g      = (const float*)d_in[6];
  const float* ln_b      = (const float*)d_in[7];
  const float* pos_table = (const float*)d_in[8];
  const float* mem_keys  = (const float*)d_in[9];
  const float* mem_vals  = (const float*)d_in[10];
  const float* mem_age   = (const float*)d_in[11];
  const float* mem_conf  = (const float*)d_in[12];
  const int*   slot_order= (const int*)d_in[13];

  char* ws = (char*)d_ws;
  u16*   A    = (u16*)(ws + 0);            // A_ext bf16 [16384][1088]  35.7 MB
  u16*   Wcat = (u16*)(ws + 36700160);     // Wcat_ext bf16 [2048][1088] 4.5 MB
  u16*   Vcat = (u16*)(ws + 41943040);     // Vcat bf16 [2048][64]     256 KB
  u16*   yb   = (u16*)(ws + 42205184);     // y bf16 [16384][1024]      32 MB
  float* y    = (float*)d_out;

  hipLaunchKernelGGL(k_front, dim3(320),  dim3(256),  0, stream,
                     x, gate_w, out_w, key_w, mem_vals, mem_keys, pos_table,
                     slot_order, mem_age, mem_conf, A, Wcat, Vcat);
  hipLaunchKernelGGL(k_gemm,  dim3(512),  dim3(1024), 0, stream,
                     A, Wcat, Vcat, out_b, gate_b, yb);
  hipLaunchKernelGGL(k_ln,    dim3(4096), dim3(256),  0, stream,
                     yb, ln_g, ln_b, y);
}